// Round 1
// baseline (1388.833 us; speedup 1.0000x reference)
//
#include <hip/hip_runtime.h>
#include <hip/hip_bf16.h>

#define N_NODES 50000
#define N_EDGES 1250000
#define D 64
#define N_GRAPHS 128
#define D_OUT 16

// ---------------------------------------------------------------------------
// Scatter: agg[dst[e]*64+f] += h[src[e]*64+f], one thread per (edge, feat).
// All 64 lanes of a wave share one edge -> src/dst loads are wave-uniform
// (scalarized), h row read is one coalesced 256B transaction.
// ---------------------------------------------------------------------------
__global__ __launch_bounds__(256) void scatter_add_kernel(
    const float* __restrict__ h, const int* __restrict__ src,
    const int* __restrict__ dst, float* __restrict__ agg, int n_edges) {
  long long idx = (long long)blockIdx.x * 256 + threadIdx.x;
  int e = (int)(idx >> 6);
  int f = (int)(idx & 63);
  if (e >= n_edges) return;
  int s = src[e];
  int d = dst[e];
  atomicAdd(&agg[(long long)d * D + f], h[(long long)s * D + f]);
}

// ---------------------------------------------------------------------------
// Fused GraphConv dense part: out = [relu](agg @ W_rel + b_rel + h @ W_root)
// Both 64x64 weight matrices live in LDS (32 KB). Thread = (node, out-feat):
// 256 threads/block -> 4 nodes/block. W access sWrel[k*64+o]: lane o
// consecutive -> 2 lanes/bank (free on CDNA4).
// ---------------------------------------------------------------------------
__global__ __launch_bounds__(256) void graphconv_gemm_kernel(
    const float* __restrict__ agg, const float* __restrict__ h,
    const float* __restrict__ Wrel, const float* __restrict__ brel,
    const float* __restrict__ Wroot, float* __restrict__ out,
    int n_nodes, int do_relu) {
  __shared__ float sWrel[D * D];
  __shared__ float sWroot[D * D];
  for (int i = threadIdx.x; i < D * D; i += 256) {
    sWrel[i] = Wrel[i];
    sWroot[i] = Wroot[i];
  }
  __syncthreads();

  int tid = blockIdx.x * 256 + threadIdx.x;
  int n = tid >> 6;
  int o = tid & 63;
  if (n >= n_nodes) return;

  const float* ar = agg + (long long)n * D;
  const float* xr = h + (long long)n * D;
  float acc = brel[o];
#pragma unroll
  for (int k = 0; k < D; k++) {
    acc = fmaf(ar[k], sWrel[k * D + o], acc);
    acc = fmaf(xr[k], sWroot[k * D + o], acc);
  }
  if (do_relu) acc = fmaxf(acc, 0.0f);
  out[(long long)n * D + o] = acc;
}

// ---------------------------------------------------------------------------
// Pool: sums[batch[n]*64+f] += h[n*64+f]; counts[batch[n]] += 1 (f==0 lane).
// ---------------------------------------------------------------------------
__global__ __launch_bounds__(256) void pool_kernel(
    const float* __restrict__ h, const int* __restrict__ batch,
    float* __restrict__ sums, float* __restrict__ counts, int n_nodes) {
  long long idx = (long long)blockIdx.x * 256 + threadIdx.x;
  int n = (int)(idx >> 6);
  int f = (int)(idx & 63);
  if (n >= n_nodes) return;
  int g = batch[n];
  atomicAdd(&sums[g * D + f], h[(long long)n * D + f]);
  if (f == 0) atomicAdd(&counts[g], 1.0f);
}

// ---------------------------------------------------------------------------
// Final: out[g,o] = (sums[g,:]/max(count,1)) @ W_lin + b_lin.  128x16 = 2048.
// ---------------------------------------------------------------------------
__global__ __launch_bounds__(256) void final_kernel(
    const float* __restrict__ sums, const float* __restrict__ counts,
    const float* __restrict__ Wlin, const float* __restrict__ blin,
    float* __restrict__ out) {
  int idx = blockIdx.x * 256 + threadIdx.x;
  if (idx >= N_GRAPHS * D_OUT) return;
  int g = idx >> 4;
  int o = idx & 15;
  float inv = 1.0f / fmaxf(counts[g], 1.0f);
  float acc = blin[o];
#pragma unroll
  for (int k = 0; k < D; k++) {
    acc = fmaf(sums[g * D + k] * inv, Wlin[k * D_OUT + o], acc);
  }
  out[idx] = acc;
}

extern "C" void kernel_launch(void* const* d_in, const int* in_sizes, int n_in,
                              void* d_out, int out_size, void* d_ws, size_t ws_size,
                              hipStream_t stream) {
  const float* x     = (const float*)d_in[0];
  const int*   ei    = (const int*)d_in[1];
  // d_in[2] = adj (unused)
  const int*   batch = (const int*)d_in[3];
  const float* Wrel1 = (const float*)d_in[4];
  const float* brel1 = (const float*)d_in[5];
  const float* Wroot1= (const float*)d_in[6];
  const float* Wrel2 = (const float*)d_in[7];
  const float* brel2 = (const float*)d_in[8];
  const float* Wroot2= (const float*)d_in[9];
  const float* Wrel3 = (const float*)d_in[10];
  const float* brel3 = (const float*)d_in[11];
  const float* Wroot3= (const float*)d_in[12];
  const float* Wlin  = (const float*)d_in[13];
  const float* blin  = (const float*)d_in[14];
  float* out = (float*)d_out;

  const int n_edges = in_sizes[1] / 2;
  const int n_nodes = in_sizes[0] / D;
  const int* src = ei;
  const int* dst = ei + n_edges;

  float* ws    = (float*)d_ws;
  float* agg   = ws;                       // [N, 64]
  float* hA    = agg + (size_t)n_nodes * D;  // [N, 64]
  float* hB    = hA + (size_t)n_nodes * D;   // [N, 64]
  float* sums  = hB + (size_t)n_nodes * D;   // [128, 64]
  float* cnts  = sums + N_GRAPHS * D;        // [128]

  const int scatter_blocks = (int)(((long long)n_edges * D + 255) / 256);
  const int gemm_blocks    = (int)(((long long)n_nodes * D + 255) / 256);

  // ---- layer 1 ----
  hipMemsetAsync(agg, 0, (size_t)n_nodes * D * sizeof(float), stream);
  scatter_add_kernel<<<scatter_blocks, 256, 0, stream>>>(x, src, dst, agg, n_edges);
  graphconv_gemm_kernel<<<gemm_blocks, 256, 0, stream>>>(agg, x, Wrel1, brel1, Wroot1, hA, n_nodes, 1);

  // ---- layer 2 ----
  hipMemsetAsync(agg, 0, (size_t)n_nodes * D * sizeof(float), stream);
  scatter_add_kernel<<<scatter_blocks, 256, 0, stream>>>(hA, src, dst, agg, n_edges);
  graphconv_gemm_kernel<<<gemm_blocks, 256, 0, stream>>>(agg, hA, Wrel2, brel2, Wroot2, hB, n_nodes, 1);

  // ---- layer 3 (no relu) ----
  hipMemsetAsync(agg, 0, (size_t)n_nodes * D * sizeof(float), stream);
  scatter_add_kernel<<<scatter_blocks, 256, 0, stream>>>(hB, src, dst, agg, n_edges);
  graphconv_gemm_kernel<<<gemm_blocks, 256, 0, stream>>>(agg, hB, Wrel3, brel3, Wroot3, hA, n_nodes, 0);

  // ---- pool + final linear ----
  hipMemsetAsync(sums, 0, (size_t)(N_GRAPHS * D + N_GRAPHS) * sizeof(float), stream);
  pool_kernel<<<gemm_blocks, 256, 0, stream>>>(hA, batch, sums, cnts, n_nodes);
  final_kernel<<<(N_GRAPHS * D_OUT + 255) / 256, 256, 0, stream>>>(sums, cnts, Wlin, blin, out);
}

// Round 2
// 805.320 us; speedup vs baseline: 1.7246x; 1.7246x over previous
//
#include <hip/hip_runtime.h>
#include <hip/hip_bf16.h>

#define D 64
#define N_GRAPHS 128
#define D_OUT 16

// ===========================================================================
// CSR build (by dst) — done once per call, reused by all 3 layers.
// ===========================================================================
__global__ __launch_bounds__(256) void deg_kernel(
    const int* __restrict__ dst, int* __restrict__ deg, int n_edges) {
  int e = blockIdx.x * 256 + threadIdx.x;
  if (e >= n_edges) return;
  atomicAdd(&deg[dst[e]], 1);
}

// Per-block inclusive scan of 256-element chunks; block totals to blockSums.
__global__ __launch_bounds__(256) void scan_block_kernel(
    const int* __restrict__ deg, int* __restrict__ incl,
    int* __restrict__ blockSums, int n) {
  __shared__ int s[256];
  int i = blockIdx.x * 256 + threadIdx.x;
  int v = (i < n) ? deg[i] : 0;
  s[threadIdx.x] = v;
  __syncthreads();
  for (int off = 1; off < 256; off <<= 1) {
    int t = (threadIdx.x >= off) ? s[threadIdx.x - off] : 0;
    __syncthreads();
    s[threadIdx.x] += t;
    __syncthreads();
  }
  if (i < n) incl[i] = s[threadIdx.x];
  if (threadIdx.x == 255) blockSums[blockIdx.x] = s[255];
}

// Single block: exclusive scan of blockSums (nb <= 256) in place.
__global__ __launch_bounds__(256) void scan_sums_kernel(
    int* __restrict__ blockSums, int nb) {
  __shared__ int s[256];
  int v = (threadIdx.x < nb) ? blockSums[threadIdx.x] : 0;
  s[threadIdx.x] = v;
  __syncthreads();
  for (int off = 1; off < 256; off <<= 1) {
    int t = (threadIdx.x >= off) ? s[threadIdx.x - off] : 0;
    __syncthreads();
    s[threadIdx.x] += t;
    __syncthreads();
  }
  if (threadIdx.x < nb) blockSums[threadIdx.x] = s[threadIdx.x] - v;  // exclusive
}

__global__ __launch_bounds__(256) void scan_add_kernel(
    const int* __restrict__ deg, const int* __restrict__ incl,
    const int* __restrict__ blockOff, int* __restrict__ offsets,
    int* __restrict__ cursor, int n) {
  int i = blockIdx.x * 256 + threadIdx.x;
  if (i >= n) return;
  int excl = incl[i] - deg[i] + blockOff[blockIdx.x];
  offsets[i] = excl;
  cursor[i] = excl;
  if (i == n - 1) offsets[n] = excl + deg[i];
}

__global__ __launch_bounds__(256) void fill_kernel(
    const int* __restrict__ src, const int* __restrict__ dst,
    int* __restrict__ cursor, int* __restrict__ csr_src, int n_edges) {
  int e = blockIdx.x * 256 + threadIdx.x;
  if (e >= n_edges) return;
  int pos = atomicAdd(&cursor[dst[e]], 1);
  csr_src[pos] = src[e];
}

// ===========================================================================
// Gather: agg[n,f] = sum over in-edges of h[src,f]. One wave per node,
// lane = feature. h row read is one coalesced 256B transaction per edge.
// ===========================================================================
__global__ __launch_bounds__(256) void gather_kernel(
    const float* __restrict__ h, const int* __restrict__ offsets,
    const int* __restrict__ csr_src, float* __restrict__ agg, int n_nodes) {
  int node = blockIdx.x * 4 + (threadIdx.x >> 6);
  int f = threadIdx.x & 63;
  if (node >= n_nodes) return;
  int start = offsets[node];
  int end = offsets[node + 1];
  float acc = 0.0f;
  int s = (start < end) ? csr_src[start] : 0;
  for (int i = start; i < end; i++) {
    int s_next = (i + 1 < end) ? csr_src[i + 1] : 0;  // prefetch index
    acc += h[(size_t)s * D + f];
    s = s_next;
  }
  agg[(size_t)node * D + f] = acc;
}

// ===========================================================================
// Fused GraphConv dense part: out = [relu](agg @ W_rel + b_rel + h @ W_root)
// ===========================================================================
__global__ __launch_bounds__(256) void graphconv_gemm_kernel(
    const float* __restrict__ agg, const float* __restrict__ h,
    const float* __restrict__ Wrel, const float* __restrict__ brel,
    const float* __restrict__ Wroot, float* __restrict__ out,
    int n_nodes, int do_relu) {
  __shared__ float sWrel[D * D];
  __shared__ float sWroot[D * D];
  for (int i = threadIdx.x; i < D * D; i += 256) {
    sWrel[i] = Wrel[i];
    sWroot[i] = Wroot[i];
  }
  __syncthreads();

  int tid = blockIdx.x * 256 + threadIdx.x;
  int n = tid >> 6;
  int o = tid & 63;
  if (n >= n_nodes) return;

  const float* ar = agg + (size_t)n * D;
  const float* xr = h + (size_t)n * D;
  float acc = brel[o];
#pragma unroll
  for (int k = 0; k < D; k++) {
    acc = fmaf(ar[k], sWrel[k * D + o], acc);
    acc = fmaf(xr[k], sWroot[k * D + o], acc);
  }
  if (do_relu) acc = fmaxf(acc, 0.0f);
  out[(size_t)n * D + o] = acc;
}

// ===========================================================================
// Pool: batch is SORTED -> graph g owns a contiguous node range. One block
// per graph: binary-search bounds, segmented reduce, write the mean.
// ===========================================================================
__global__ __launch_bounds__(256) void pool_mean_kernel(
    const float* __restrict__ h, const int* __restrict__ batch,
    float* __restrict__ pooled, int n_nodes) {
  __shared__ int seg[2];
  __shared__ float red[256];
  int g = blockIdx.x;
  if (threadIdx.x < 2) {
    int target = g + (int)threadIdx.x;  // lower_bound(target)
    int lo = 0, hi = n_nodes;
    while (lo < hi) {
      int mid = (lo + hi) >> 1;
      if (batch[mid] < target) lo = mid + 1; else hi = mid;
    }
    seg[threadIdx.x] = lo;
  }
  __syncthreads();
  int start = seg[0], end = seg[1];
  int f = threadIdx.x & 63, sub = threadIdx.x >> 6;
  float acc = 0.0f;
  for (int n = start + sub; n < end; n += 4) acc += h[(size_t)n * D + f];
  red[threadIdx.x] = acc;
  __syncthreads();
  if (sub == 0) {
    float v = red[f] + red[64 + f] + red[128 + f] + red[192 + f];
    float cnt = (float)(end - start);
    pooled[g * D + f] = v / fmaxf(cnt, 1.0f);
  }
}

// ===========================================================================
// Final: out[g,o] = pooled[g,:] @ W_lin + b_lin.   128x16 outputs.
// ===========================================================================
__global__ __launch_bounds__(256) void final_kernel(
    const float* __restrict__ pooled, const float* __restrict__ Wlin,
    const float* __restrict__ blin, float* __restrict__ out) {
  int idx = blockIdx.x * 256 + threadIdx.x;
  if (idx >= N_GRAPHS * D_OUT) return;
  int g = idx >> 4;
  int o = idx & 15;
  float acc = blin[o];
#pragma unroll
  for (int k = 0; k < D; k++) {
    acc = fmaf(pooled[g * D + k], Wlin[k * D_OUT + o], acc);
  }
  out[idx] = acc;
}

extern "C" void kernel_launch(void* const* d_in, const int* in_sizes, int n_in,
                              void* d_out, int out_size, void* d_ws, size_t ws_size,
                              hipStream_t stream) {
  const float* x     = (const float*)d_in[0];
  const int*   ei    = (const int*)d_in[1];
  const int*   batch = (const int*)d_in[3];
  const float* Wrel1 = (const float*)d_in[4];
  const float* brel1 = (const float*)d_in[5];
  const float* Wroot1= (const float*)d_in[6];
  const float* Wrel2 = (const float*)d_in[7];
  const float* brel2 = (const float*)d_in[8];
  const float* Wroot2= (const float*)d_in[9];
  const float* Wrel3 = (const float*)d_in[10];
  const float* brel3 = (const float*)d_in[11];
  const float* Wroot3= (const float*)d_in[12];
  const float* Wlin  = (const float*)d_in[13];
  const float* blin  = (const float*)d_in[14];
  float* out = (float*)d_out;

  const int n_edges = in_sizes[1] / 2;
  const int n_nodes = in_sizes[0] / D;
  const int* src = ei;
  const int* dst = ei + n_edges;

  // ---- workspace carve-up ----
  char* p = (char*)d_ws;
  float* agg    = (float*)p; p += (size_t)n_nodes * D * sizeof(float);
  float* hA     = (float*)p; p += (size_t)n_nodes * D * sizeof(float);
  float* hB     = (float*)p; p += (size_t)n_nodes * D * sizeof(float);
  float* pooled = (float*)p; p += (size_t)N_GRAPHS * D * sizeof(float);
  int* deg      = (int*)p;   p += (size_t)n_nodes * sizeof(int);
  int* incl     = (int*)p;   p += (size_t)n_nodes * sizeof(int);
  int* blockOff = (int*)p;   p += 256 * sizeof(int);
  int* offsets  = (int*)p;   p += (size_t)(n_nodes + 1) * sizeof(int);
  int* cursor   = (int*)p;   p += (size_t)n_nodes * sizeof(int);
  int* csr_src  = (int*)p;   p += (size_t)n_edges * sizeof(int);

  const int edge_blocks = (n_edges + 255) / 256;
  const int node_blocks = (n_nodes + 255) / 256;   // 196 (<=256, required by scan)
  const int gemm_blocks = (int)(((size_t)n_nodes * D + 255) / 256);
  const int gath_blocks = (n_nodes + 3) / 4;

  // ---- CSR build (once) ----
  hipMemsetAsync(deg, 0, (size_t)n_nodes * sizeof(int), stream);
  deg_kernel<<<edge_blocks, 256, 0, stream>>>(dst, deg, n_edges);
  scan_block_kernel<<<node_blocks, 256, 0, stream>>>(deg, incl, blockOff, n_nodes);
  scan_sums_kernel<<<1, 256, 0, stream>>>(blockOff, node_blocks);
  scan_add_kernel<<<node_blocks, 256, 0, stream>>>(deg, incl, blockOff, offsets, cursor, n_nodes);
  fill_kernel<<<edge_blocks, 256, 0, stream>>>(src, dst, cursor, csr_src, n_edges);

  // ---- layer 1 ----
  gather_kernel<<<gath_blocks, 256, 0, stream>>>(x, offsets, csr_src, agg, n_nodes);
  graphconv_gemm_kernel<<<gemm_blocks, 256, 0, stream>>>(agg, x, Wrel1, brel1, Wroot1, hA, n_nodes, 1);

  // ---- layer 2 ----
  gather_kernel<<<gath_blocks, 256, 0, stream>>>(hA, offsets, csr_src, agg, n_nodes);
  graphconv_gemm_kernel<<<gemm_blocks, 256, 0, stream>>>(agg, hA, Wrel2, brel2, Wroot2, hB, n_nodes, 1);

  // ---- layer 3 (no relu) ----
  gather_kernel<<<gath_blocks, 256, 0, stream>>>(hB, offsets, csr_src, agg, n_nodes);
  graphconv_gemm_kernel<<<gemm_blocks, 256, 0, stream>>>(agg, hB, Wrel3, brel3, Wroot3, hA, n_nodes, 0);

  // ---- pool + final linear ----
  pool_mean_kernel<<<N_GRAPHS, 256, 0, stream>>>(hA, batch, pooled, n_nodes);
  final_kernel<<<(N_GRAPHS * D_OUT + 255) / 256, 256, 0, stream>>>(pooled, Wlin, blin, out);
}

// Round 3
// 519.573 us; speedup vs baseline: 2.6730x; 1.5500x over previous
//
#include <hip/hip_runtime.h>
#include <hip/hip_bf16.h>

#define D 64
#define N_GRAPHS 128
#define D_OUT 16

// ===========================================================================
// CSR build (by dst) — once per call, reused by all 3 layers.
// ===========================================================================
__global__ __launch_bounds__(256) void deg_kernel(
    const int* __restrict__ dst, int* __restrict__ deg, int n_edges) {
  int e = blockIdx.x * 256 + threadIdx.x;
  if (e >= n_edges) return;
  atomicAdd(&deg[dst[e]], 1);
}

__global__ __launch_bounds__(256) void scan_block_kernel(
    const int* __restrict__ deg, int* __restrict__ incl,
    int* __restrict__ blockSums, int n) {
  __shared__ int s[256];
  int i = blockIdx.x * 256 + threadIdx.x;
  int v = (i < n) ? deg[i] : 0;
  s[threadIdx.x] = v;
  __syncthreads();
  for (int off = 1; off < 256; off <<= 1) {
    int t = (threadIdx.x >= off) ? s[threadIdx.x - off] : 0;
    __syncthreads();
    s[threadIdx.x] += t;
    __syncthreads();
  }
  if (i < n) incl[i] = s[threadIdx.x];
  if (threadIdx.x == 255) blockSums[blockIdx.x] = s[255];
}

__global__ __launch_bounds__(256) void scan_sums_kernel(
    int* __restrict__ blockSums, int nb) {
  __shared__ int s[256];
  int v = (threadIdx.x < nb) ? blockSums[threadIdx.x] : 0;
  s[threadIdx.x] = v;
  __syncthreads();
  for (int off = 1; off < 256; off <<= 1) {
    int t = (threadIdx.x >= off) ? s[threadIdx.x - off] : 0;
    __syncthreads();
    s[threadIdx.x] += t;
    __syncthreads();
  }
  if (threadIdx.x < nb) blockSums[threadIdx.x] = s[threadIdx.x] - v;  // exclusive
}

__global__ __launch_bounds__(256) void scan_add_kernel(
    const int* __restrict__ deg, const int* __restrict__ incl,
    const int* __restrict__ blockOff, int* __restrict__ offsets,
    int* __restrict__ cursor, int n) {
  int i = blockIdx.x * 256 + threadIdx.x;
  if (i >= n) return;
  int excl = incl[i] - deg[i] + blockOff[blockIdx.x];
  offsets[i] = excl;
  cursor[i] = excl;
  if (i == n - 1) offsets[n] = excl + deg[i];
}

__global__ __launch_bounds__(256) void fill_kernel(
    const int* __restrict__ src, const int* __restrict__ dst,
    int* __restrict__ cursor, int* __restrict__ csr_src, int n_edges) {
  int e = blockIdx.x * 256 + threadIdx.x;
  if (e >= n_edges) return;
  int pos = atomicAdd(&cursor[dst[e]], 1);
  csr_src[pos] = src[e];
}

// ===========================================================================
// Gather v2: wave = node. 4 subgroups of 16 lanes; subgroup handles every
// 4th edge, each lane loads float4 (16B). Unroll x2 with 2 accumulators ->
// up to 8 row-loads in flight per wave (vs 1 in v1, which was latency-bound
// at ~58 cyc/load). Final reduce across subgroups via shfl_xor 16/32.
// ===========================================================================
__global__ __launch_bounds__(256) void gather_kernel(
    const float* __restrict__ h, const int* __restrict__ offsets,
    const int* __restrict__ csr_src, float* __restrict__ agg, int n_nodes) {
  int node = blockIdx.x * 4 + (threadIdx.x >> 6);
  int lane = threadIdx.x & 63;
  int sub = lane >> 4;          // 0..3: which edge of each group of 4
  int fo = (lane & 15) * 4;     // feature offset (float4)
  if (node >= n_nodes) return;
  int start = offsets[node];
  int end = offsets[node + 1];

  float4 a0 = {0.f, 0.f, 0.f, 0.f};
  float4 a1 = {0.f, 0.f, 0.f, 0.f};
  int i = start + sub;
  for (; i + 4 < end; i += 8) {
    int s0 = csr_src[i];
    int s1 = csr_src[i + 4];
    float4 r0 = *(const float4*)(h + (size_t)s0 * D + fo);
    float4 r1 = *(const float4*)(h + (size_t)s1 * D + fo);
    a0.x += r0.x; a0.y += r0.y; a0.z += r0.z; a0.w += r0.w;
    a1.x += r1.x; a1.y += r1.y; a1.z += r1.z; a1.w += r1.w;
  }
  if (i < end) {
    int s0 = csr_src[i];
    float4 r0 = *(const float4*)(h + (size_t)s0 * D + fo);
    a0.x += r0.x; a0.y += r0.y; a0.z += r0.z; a0.w += r0.w;
  }
  a0.x += a1.x; a0.y += a1.y; a0.z += a1.z; a0.w += a1.w;

  // reduce across the 4 subgroups (lanes xor 16, xor 32)
  a0.x += __shfl_xor(a0.x, 16); a0.y += __shfl_xor(a0.y, 16);
  a0.z += __shfl_xor(a0.z, 16); a0.w += __shfl_xor(a0.w, 16);
  a0.x += __shfl_xor(a0.x, 32); a0.y += __shfl_xor(a0.y, 32);
  a0.z += __shfl_xor(a0.z, 32); a0.w += __shfl_xor(a0.w, 32);

  if (sub == 0) *(float4*)(agg + (size_t)node * D + fo) = a0;
}

// ===========================================================================
// Dense v2: out = [relu](agg @ W_rel + b + h @ W_root), weights in REGISTERS
// (lane o holds column o of both matrices: 128 VGPRs), persistent grid.
// agg[k]/x[k] broadcast via v_readlane (k is a compile-time constant in the
// unrolled loop) -> zero LDS traffic, pure VALU.
// ===========================================================================
__global__ __launch_bounds__(64) void dense_kernel(
    const float* __restrict__ agg, const float* __restrict__ h,
    const float* __restrict__ Wrel, const float* __restrict__ brel,
    const float* __restrict__ Wroot, float* __restrict__ out,
    int n_nodes, int do_relu) {
  int lane = threadIdx.x;  // 0..63 = output feature
  float wrel[D], wroot[D];
#pragma unroll
  for (int k = 0; k < D; k++) {
    wrel[k] = Wrel[k * D + lane];
    wroot[k] = Wroot[k * D + lane];
  }
  float b = brel[lane];

  for (int n = blockIdx.x; n < n_nodes; n += gridDim.x) {
    float va = agg[(size_t)n * D + lane];
    float vx = h[(size_t)n * D + lane];
    float acc = b;
#pragma unroll
    for (int k = 0; k < D; k++) {
      float sa = __int_as_float(__builtin_amdgcn_readlane(__float_as_int(va), k));
      float sx = __int_as_float(__builtin_amdgcn_readlane(__float_as_int(vx), k));
      acc = fmaf(sa, wrel[k], acc);
      acc = fmaf(sx, wroot[k], acc);
    }
    if (do_relu) acc = fmaxf(acc, 0.0f);
    out[(size_t)n * D + lane] = acc;
  }
}

// ===========================================================================
// Pool: batch sorted -> contiguous segments; one block per graph.
// ===========================================================================
__global__ __launch_bounds__(256) void pool_mean_kernel(
    const float* __restrict__ h, const int* __restrict__ batch,
    float* __restrict__ pooled, int n_nodes) {
  __shared__ int seg[2];
  __shared__ float red[256];
  int g = blockIdx.x;
  if (threadIdx.x < 2) {
    int target = g + (int)threadIdx.x;
    int lo = 0, hi = n_nodes;
    while (lo < hi) {
      int mid = (lo + hi) >> 1;
      if (batch[mid] < target) lo = mid + 1; else hi = mid;
    }
    seg[threadIdx.x] = lo;
  }
  __syncthreads();
  int start = seg[0], end = seg[1];
  int f = threadIdx.x & 63, sub = threadIdx.x >> 6;
  float acc = 0.0f;
  for (int n = start + sub; n < end; n += 4) acc += h[(size_t)n * D + f];
  red[threadIdx.x] = acc;
  __syncthreads();
  if (sub == 0) {
    float v = red[f] + red[64 + f] + red[128 + f] + red[192 + f];
    float cnt = (float)(end - start);
    pooled[g * D + f] = v / fmaxf(cnt, 1.0f);
  }
}

__global__ __launch_bounds__(256) void final_kernel(
    const float* __restrict__ pooled, const float* __restrict__ Wlin,
    const float* __restrict__ blin, float* __restrict__ out) {
  int idx = blockIdx.x * 256 + threadIdx.x;
  if (idx >= N_GRAPHS * D_OUT) return;
  int g = idx >> 4;
  int o = idx & 15;
  float acc = blin[o];
#pragma unroll
  for (int k = 0; k < D; k++) {
    acc = fmaf(pooled[g * D + k], Wlin[k * D_OUT + o], acc);
  }
  out[idx] = acc;
}

extern "C" void kernel_launch(void* const* d_in, const int* in_sizes, int n_in,
                              void* d_out, int out_size, void* d_ws, size_t ws_size,
                              hipStream_t stream) {
  const float* x     = (const float*)d_in[0];
  const int*   ei    = (const int*)d_in[1];
  const int*   batch = (const int*)d_in[3];
  const float* Wrel1 = (const float*)d_in[4];
  const float* brel1 = (const float*)d_in[5];
  const float* Wroot1= (const float*)d_in[6];
  const float* Wrel2 = (const float*)d_in[7];
  const float* brel2 = (const float*)d_in[8];
  const float* Wroot2= (const float*)d_in[9];
  const float* Wrel3 = (const float*)d_in[10];
  const float* brel3 = (const float*)d_in[11];
  const float* Wroot3= (const float*)d_in[12];
  const float* Wlin  = (const float*)d_in[13];
  const float* blin  = (const float*)d_in[14];
  float* out = (float*)d_out;

  const int n_edges = in_sizes[1] / 2;
  const int n_nodes = in_sizes[0] / D;
  const int* src = ei;
  const int* dst = ei + n_edges;

  // ---- workspace carve-up ----
  char* p = (char*)d_ws;
  float* agg    = (float*)p; p += (size_t)n_nodes * D * sizeof(float);
  float* hA     = (float*)p; p += (size_t)n_nodes * D * sizeof(float);
  float* hB     = (float*)p; p += (size_t)n_nodes * D * sizeof(float);
  float* pooled = (float*)p; p += (size_t)N_GRAPHS * D * sizeof(float);
  int* deg      = (int*)p;   p += (size_t)n_nodes * sizeof(int);
  int* incl     = (int*)p;   p += (size_t)n_nodes * sizeof(int);
  int* blockOff = (int*)p;   p += 256 * sizeof(int);
  int* offsets  = (int*)p;   p += (size_t)(n_nodes + 1) * sizeof(int);
  int* cursor   = (int*)p;   p += (size_t)n_nodes * sizeof(int);
  int* csr_src  = (int*)p;   p += (size_t)n_edges * sizeof(int);

  const int edge_blocks = (n_edges + 255) / 256;
  const int node_blocks = (n_nodes + 255) / 256;   // <=256 required by scan
  const int gath_blocks = (n_nodes + 3) / 4;
  const int dense_blocks = 2048;                   // persistent, 64-thr blocks

  // ---- CSR build (once) ----
  hipMemsetAsync(deg, 0, (size_t)n_nodes * sizeof(int), stream);
  deg_kernel<<<edge_blocks, 256, 0, stream>>>(dst, deg, n_edges);
  scan_block_kernel<<<node_blocks, 256, 0, stream>>>(deg, incl, blockOff, n_nodes);
  scan_sums_kernel<<<1, 256, 0, stream>>>(blockOff, node_blocks);
  scan_add_kernel<<<node_blocks, 256, 0, stream>>>(deg, incl, blockOff, offsets, cursor, n_nodes);
  fill_kernel<<<edge_blocks, 256, 0, stream>>>(src, dst, cursor, csr_src, n_edges);

  // ---- layer 1 ----
  gather_kernel<<<gath_blocks, 256, 0, stream>>>(x, offsets, csr_src, agg, n_nodes);
  dense_kernel<<<dense_blocks, 64, 0, stream>>>(agg, x, Wrel1, brel1, Wroot1, hA, n_nodes, 1);

  // ---- layer 2 ----
  gather_kernel<<<gath_blocks, 256, 0, stream>>>(hA, offsets, csr_src, agg, n_nodes);
  dense_kernel<<<dense_blocks, 64, 0, stream>>>(agg, hA, Wrel2, brel2, Wroot2, hB, n_nodes, 1);

  // ---- layer 3 (no relu) ----
  gather_kernel<<<gath_blocks, 256, 0, stream>>>(hB, offsets, csr_src, agg, n_nodes);
  dense_kernel<<<dense_blocks, 64, 0, stream>>>(agg, hB, Wrel3, brel3, Wroot3, hA, n_nodes, 0);

  // ---- pool + final linear ----
  pool_mean_kernel<<<N_GRAPHS, 256, 0, stream>>>(hA, batch, pooled, n_nodes);
  final_kernel<<<(N_GRAPHS * D_OUT + 255) / 256, 256, 0, stream>>>(pooled, Wlin, blin, out);
}

// Round 4
// 503.388 us; speedup vs baseline: 2.7590x; 1.0322x over previous
//
#include <hip/hip_runtime.h>
#include <hip/hip_bf16.h>

#define D 64
#define N_GRAPHS 128
#define D_OUT 16

typedef unsigned short u16;
typedef unsigned int u32;

__device__ inline u16 f2bf(float f) {  // round-to-nearest-even
  u32 u = __float_as_uint(f);
  return (u16)((u + 0x7fffu + ((u >> 16) & 1u)) >> 16);
}
__device__ inline float bf2f(u16 b) { return __uint_as_float((u32)b << 16); }

// ===========================================================================
// x (fp32) -> bf16, 4 elems/thread.
// ===========================================================================
__global__ __launch_bounds__(256) void cvt_bf16_kernel(
    const float* __restrict__ in, u16* __restrict__ out, int n4) {
  int i = blockIdx.x * 256 + threadIdx.x;
  if (i >= n4) return;
  float4 v = ((const float4*)in)[i];
  ushort4 o;
  o.x = f2bf(v.x); o.y = f2bf(v.y); o.z = f2bf(v.z); o.w = f2bf(v.w);
  ((ushort4*)out)[i] = o;
}

// ===========================================================================
// CSR build (by dst) — once per call, reused by all 3 layers.
// ===========================================================================
__global__ __launch_bounds__(256) void deg_kernel(
    const int* __restrict__ dst, int* __restrict__ deg, int n_edges) {
  int e = blockIdx.x * 256 + threadIdx.x;
  if (e >= n_edges) return;
  atomicAdd(&deg[dst[e]], 1);
}

__global__ __launch_bounds__(256) void scan_block_kernel(
    const int* __restrict__ deg, int* __restrict__ incl,
    int* __restrict__ blockSums, int n) {
  __shared__ int s[256];
  int i = blockIdx.x * 256 + threadIdx.x;
  int v = (i < n) ? deg[i] : 0;
  s[threadIdx.x] = v;
  __syncthreads();
  for (int off = 1; off < 256; off <<= 1) {
    int t = (threadIdx.x >= off) ? s[threadIdx.x - off] : 0;
    __syncthreads();
    s[threadIdx.x] += t;
    __syncthreads();
  }
  if (i < n) incl[i] = s[threadIdx.x];
  if (threadIdx.x == 255) blockSums[blockIdx.x] = s[255];
}

__global__ __launch_bounds__(256) void scan_sums_kernel(
    int* __restrict__ blockSums, int nb) {
  __shared__ int s[256];
  int v = (threadIdx.x < nb) ? blockSums[threadIdx.x] : 0;
  s[threadIdx.x] = v;
  __syncthreads();
  for (int off = 1; off < 256; off <<= 1) {
    int t = (threadIdx.x >= off) ? s[threadIdx.x - off] : 0;
    __syncthreads();
    s[threadIdx.x] += t;
    __syncthreads();
  }
  if (threadIdx.x < nb) blockSums[threadIdx.x] = s[threadIdx.x] - v;  // exclusive
}

__global__ __launch_bounds__(256) void scan_add_kernel(
    const int* __restrict__ deg, const int* __restrict__ incl,
    const int* __restrict__ blockOff, int* __restrict__ offsets,
    int* __restrict__ cursor, int n) {
  int i = blockIdx.x * 256 + threadIdx.x;
  if (i >= n) return;
  int excl = incl[i] - deg[i] + blockOff[blockIdx.x];
  offsets[i] = excl;
  cursor[i] = excl;
  if (i == n - 1) offsets[n] = excl + deg[i];
}

__global__ __launch_bounds__(256) void fill_kernel(
    const int* __restrict__ src, const int* __restrict__ dst,
    int* __restrict__ cursor, u16* __restrict__ csr_src, int n_edges) {
  int e = blockIdx.x * 256 + threadIdx.x;
  if (e >= n_edges) return;
  int pos = atomicAdd(&cursor[dst[e]], 1);
  csr_src[pos] = (u16)src[e];
}

// ===========================================================================
// Gather v3 (bf16 rows): wave = node. 8 subgroups of 8 lanes; each lane
// loads 16B = 8 bf16 feats -> 8 random 128B rows in flight per load instr,
// x2 unroll. fp32 accumulate; agg stays fp32. Reduce via shfl_xor 8/16/32.
// ===========================================================================
__global__ __launch_bounds__(256) void gather_kernel(
    const u16* __restrict__ h, const int* __restrict__ offsets,
    const u16* __restrict__ csr_src, float* __restrict__ agg, int n_nodes) {
  int node = blockIdx.x * 4 + (threadIdx.x >> 6);
  int lane = threadIdx.x & 63;
  int sub = lane >> 3;          // 0..7
  int fo = (lane & 7) * 8;      // feature offset (8 bf16 = 16B)
  if (node >= n_nodes) return;
  int start = offsets[node];
  int end = offsets[node + 1];

  float a0[8] = {0, 0, 0, 0, 0, 0, 0, 0};
  float a1[8] = {0, 0, 0, 0, 0, 0, 0, 0};
  int i = start + sub;
  for (; i + 8 < end; i += 16) {
    int s0 = csr_src[i];
    int s1 = csr_src[i + 8];
    uint4 r0 = *(const uint4*)(h + ((size_t)s0 << 6) + fo);
    uint4 r1 = *(const uint4*)(h + ((size_t)s1 << 6) + fo);
    a0[0] += __uint_as_float(r0.x << 16); a0[1] += __uint_as_float(r0.x & 0xffff0000u);
    a0[2] += __uint_as_float(r0.y << 16); a0[3] += __uint_as_float(r0.y & 0xffff0000u);
    a0[4] += __uint_as_float(r0.z << 16); a0[5] += __uint_as_float(r0.z & 0xffff0000u);
    a0[6] += __uint_as_float(r0.w << 16); a0[7] += __uint_as_float(r0.w & 0xffff0000u);
    a1[0] += __uint_as_float(r1.x << 16); a1[1] += __uint_as_float(r1.x & 0xffff0000u);
    a1[2] += __uint_as_float(r1.y << 16); a1[3] += __uint_as_float(r1.y & 0xffff0000u);
    a1[4] += __uint_as_float(r1.z << 16); a1[5] += __uint_as_float(r1.z & 0xffff0000u);
    a1[6] += __uint_as_float(r1.w << 16); a1[7] += __uint_as_float(r1.w & 0xffff0000u);
  }
  if (i < end) {
    int s0 = csr_src[i];
    uint4 r0 = *(const uint4*)(h + ((size_t)s0 << 6) + fo);
    a0[0] += __uint_as_float(r0.x << 16); a0[1] += __uint_as_float(r0.x & 0xffff0000u);
    a0[2] += __uint_as_float(r0.y << 16); a0[3] += __uint_as_float(r0.y & 0xffff0000u);
    a0[4] += __uint_as_float(r0.z << 16); a0[5] += __uint_as_float(r0.z & 0xffff0000u);
    a0[6] += __uint_as_float(r0.w << 16); a0[7] += __uint_as_float(r0.w & 0xffff0000u);
  }
#pragma unroll
  for (int k = 0; k < 8; k++) a0[k] += a1[k];
#pragma unroll
  for (int k = 0; k < 8; k++) {
    a0[k] += __shfl_xor(a0[k], 8);
    a0[k] += __shfl_xor(a0[k], 16);
    a0[k] += __shfl_xor(a0[k], 32);
  }
  if (sub == 0) {
    float* ap = agg + ((size_t)node << 6) + fo;
    *(float4*)(ap)     = make_float4(a0[0], a0[1], a0[2], a0[3]);
    *(float4*)(ap + 4) = make_float4(a0[4], a0[5], a0[6], a0[7]);
  }
}

// ===========================================================================
// Dense: out = [relu](agg @ W_rel + b + h @ W_root). Weights in registers
// (lane o holds column o), readlane broadcast, zero LDS. agg fp32, h/out bf16.
// ===========================================================================
__global__ __launch_bounds__(64) void dense_kernel(
    const float* __restrict__ agg, const u16* __restrict__ h,
    const float* __restrict__ Wrel, const float* __restrict__ brel,
    const float* __restrict__ Wroot, u16* __restrict__ out,
    int n_nodes, int do_relu) {
  int lane = threadIdx.x;  // 0..63 = output feature
  float wrel[D], wroot[D];
#pragma unroll
  for (int k = 0; k < D; k++) {
    wrel[k] = Wrel[k * D + lane];
    wroot[k] = Wroot[k * D + lane];
  }
  float b = brel[lane];

  for (int n = blockIdx.x; n < n_nodes; n += gridDim.x) {
    float va = agg[((size_t)n << 6) + lane];
    float vx = bf2f(h[((size_t)n << 6) + lane]);
    float acc = b;
#pragma unroll
    for (int k = 0; k < D; k++) {
      float sa = __int_as_float(__builtin_amdgcn_readlane(__float_as_int(va), k));
      float sx = __int_as_float(__builtin_amdgcn_readlane(__float_as_int(vx), k));
      acc = fmaf(sa, wrel[k], acc);
      acc = fmaf(sx, wroot[k], acc);
    }
    if (do_relu) acc = fmaxf(acc, 0.0f);
    out[((size_t)n << 6) + lane] = f2bf(acc);
  }
}

// ===========================================================================
// Pool: batch sorted -> contiguous segments; one block per graph. bf16 in,
// fp32 accumulate, fp32 mean out.
// ===========================================================================
__global__ __launch_bounds__(256) void pool_mean_kernel(
    const u16* __restrict__ h, const int* __restrict__ batch,
    float* __restrict__ pooled, int n_nodes) {
  __shared__ int seg[2];
  __shared__ float red[256];
  int g = blockIdx.x;
  if (threadIdx.x < 2) {
    int target = g + (int)threadIdx.x;
    int lo = 0, hi = n_nodes;
    while (lo < hi) {
      int mid = (lo + hi) >> 1;
      if (batch[mid] < target) lo = mid + 1; else hi = mid;
    }
    seg[threadIdx.x] = lo;
  }
  __syncthreads();
  int start = seg[0], end = seg[1];
  int f = threadIdx.x & 63, sub = threadIdx.x >> 6;
  float acc = 0.0f;
  for (int n = start + sub; n < end; n += 4) acc += bf2f(h[((size_t)n << 6) + f]);
  red[threadIdx.x] = acc;
  __syncthreads();
  if (sub == 0) {
    float v = red[f] + red[64 + f] + red[128 + f] + red[192 + f];
    float cnt = (float)(end - start);
    pooled[g * D + f] = v / fmaxf(cnt, 1.0f);
  }
}

__global__ __launch_bounds__(256) void final_kernel(
    const float* __restrict__ pooled, const float* __restrict__ Wlin,
    const float* __restrict__ blin, float* __restrict__ out) {
  int idx = blockIdx.x * 256 + threadIdx.x;
  if (idx >= N_GRAPHS * D_OUT) return;
  int g = idx >> 4;
  int o = idx & 15;
  float acc = blin[o];
#pragma unroll
  for (int k = 0; k < D; k++) {
    acc = fmaf(pooled[g * D + k], Wlin[k * D_OUT + o], acc);
  }
  out[idx] = acc;
}

extern "C" void kernel_launch(void* const* d_in, const int* in_sizes, int n_in,
                              void* d_out, int out_size, void* d_ws, size_t ws_size,
                              hipStream_t stream) {
  const float* x     = (const float*)d_in[0];
  const int*   ei    = (const int*)d_in[1];
  const int*   batch = (const int*)d_in[3];
  const float* Wrel1 = (const float*)d_in[4];
  const float* brel1 = (const float*)d_in[5];
  const float* Wroot1= (const float*)d_in[6];
  const float* Wrel2 = (const float*)d_in[7];
  const float* brel2 = (const float*)d_in[8];
  const float* Wroot2= (const float*)d_in[9];
  const float* Wrel3 = (const float*)d_in[10];
  const float* brel3 = (const float*)d_in[11];
  const float* Wroot3= (const float*)d_in[12];
  const float* Wlin  = (const float*)d_in[13];
  const float* blin  = (const float*)d_in[14];
  float* out = (float*)d_out;

  const int n_edges = in_sizes[1] / 2;
  const int n_nodes = in_sizes[0] / D;
  const int* src = ei;
  const int* dst = ei + n_edges;

  // ---- workspace carve-up (16B-aligned chunks; u16 buffers last) ----
  char* p = (char*)d_ws;
  float* agg    = (float*)p; p += (size_t)n_nodes * D * sizeof(float);
  float* pooled = (float*)p; p += (size_t)N_GRAPHS * D * sizeof(float);
  int* deg      = (int*)p;   p += (size_t)n_nodes * sizeof(int);
  int* incl     = (int*)p;   p += (size_t)n_nodes * sizeof(int);
  int* blockOff = (int*)p;   p += 256 * sizeof(int);
  int* offsets  = (int*)p;   p += (size_t)(n_nodes + 4) * sizeof(int);
  int* cursor   = (int*)p;   p += (size_t)n_nodes * sizeof(int);
  u16* hX       = (u16*)p;   p += (size_t)n_nodes * D * sizeof(u16);
  u16* h1       = (u16*)p;   p += (size_t)n_nodes * D * sizeof(u16);
  u16* h2       = (u16*)p;   p += (size_t)n_nodes * D * sizeof(u16);
  u16* h3       = (u16*)p;   p += (size_t)n_nodes * D * sizeof(u16);
  u16* csr_src  = (u16*)p;   p += (size_t)n_edges * sizeof(u16);

  const int edge_blocks = (n_edges + 255) / 256;
  const int node_blocks = (n_nodes + 255) / 256;   // <=256 required by scan
  const int gath_blocks = (n_nodes + 3) / 4;
  const int dense_blocks = 2048;
  const int cvt_n4 = n_nodes * D / 4;

  // ---- CSR build + x->bf16 (once) ----
  hipMemsetAsync(deg, 0, (size_t)n_nodes * sizeof(int), stream);
  cvt_bf16_kernel<<<(cvt_n4 + 255) / 256, 256, 0, stream>>>(x, hX, cvt_n4);
  deg_kernel<<<edge_blocks, 256, 0, stream>>>(dst, deg, n_edges);
  scan_block_kernel<<<node_blocks, 256, 0, stream>>>(deg, incl, blockOff, n_nodes);
  scan_sums_kernel<<<1, 256, 0, stream>>>(blockOff, node_blocks);
  scan_add_kernel<<<node_blocks, 256, 0, stream>>>(deg, incl, blockOff, offsets, cursor, n_nodes);
  fill_kernel<<<edge_blocks, 256, 0, stream>>>(src, dst, cursor, csr_src, n_edges);

  // ---- layer 1 ----
  gather_kernel<<<gath_blocks, 256, 0, stream>>>(hX, offsets, csr_src, agg, n_nodes);
  dense_kernel<<<dense_blocks, 64, 0, stream>>>(agg, hX, Wrel1, brel1, Wroot1, h1, n_nodes, 1);

  // ---- layer 2 ----
  gather_kernel<<<gath_blocks, 256, 0, stream>>>(h1, offsets, csr_src, agg, n_nodes);
  dense_kernel<<<dense_blocks, 64, 0, stream>>>(agg, h1, Wrel2, brel2, Wroot2, h2, n_nodes, 1);

  // ---- layer 3 (no relu) ----
  gather_kernel<<<gath_blocks, 256, 0, stream>>>(h2, offsets, csr_src, agg, n_nodes);
  dense_kernel<<<dense_blocks, 64, 0, stream>>>(agg, h2, Wrel3, brel3, Wroot3, h3, n_nodes, 0);

  // ---- pool + final linear ----
  pool_mean_kernel<<<N_GRAPHS, 256, 0, stream>>>(h3, batch, pooled, n_nodes);
  final_kernel<<<(N_GRAPHS * D_OUT + 255) / 256, 256, 0, stream>>>(pooled, Wlin, blin, out);
}

// Round 5
// 345.021 us; speedup vs baseline: 4.0254x; 1.4590x over previous
//
#include <hip/hip_runtime.h>
#include <hip/hip_bf16.h>

#define D 64
#define N_GRAPHS 128
#define D_OUT 16
#define BCAP 16384   // max edges per 256-node bucket (avg 6400, sigma ~80)
#define TILE 4096    // edges per bin_kernel block

typedef unsigned short u16;
typedef unsigned int u32;
typedef unsigned char u8;

__device__ inline u16 f2bf(float f) {  // round-to-nearest-even
  u32 u = __float_as_uint(f);
  return (u16)((u + 0x7fffu + ((u >> 16) & 1u)) >> 16);
}
__device__ inline float bf2f(u16 b) { return __uint_as_float((u32)b << 16); }

// ===========================================================================
// x (fp32) -> bf16, 4 elems/thread.
// ===========================================================================
__global__ __launch_bounds__(256) void cvt_bf16_kernel(
    const float* __restrict__ in, u16* __restrict__ out, int n4) {
  int i = blockIdx.x * 256 + threadIdx.x;
  if (i >= n4) return;
  float4 v = ((const float4*)in)[i];
  ushort4 o;
  o.x = f2bf(v.x); o.y = f2bf(v.y); o.z = f2bf(v.z); o.w = f2bf(v.w);
  ((ushort4*)out)[i] = o;
}

// ===========================================================================
// CSR build v2: LDS counting sort. Old fill_kernel was bound by partial-line
// HBM writeback (1.25M scattered stores x 64B line = 81 MB, measured). Here
// all scattered work happens in LDS; global writes are contiguous.
// ===========================================================================
__global__ __launch_bounds__(256) void init_cursors_kernel(
    int* __restrict__ cursors, int nbuck) {
  int t = threadIdx.x;
  if (t < nbuck) cursors[t] = t * BCAP;
}

// Pass 1: bin edges by dst>>8. Each block sorts a 4096-edge tile in LDS,
// then copies each bucket's run to global (contiguous chunks, ~85B avg).
__global__ __launch_bounds__(256) void bin_kernel(
    const int* __restrict__ src, const int* __restrict__ dst,
    int* __restrict__ cursors, u32* __restrict__ binned,
    int n_edges, int nbuck) {
  __shared__ u32 ent[TILE];
  __shared__ u8 ebk[TILE];
  __shared__ int hist[256];
  __shared__ int startb[256];
  __shared__ int cur[256];
  __shared__ int gbase[256];
  int t = threadIdx.x;
  hist[t] = 0;
  __syncthreads();

  int base = blockIdx.x * TILE;
  int cnt = n_edges - base;
  if (cnt > TILE) cnt = TILE;

  int mys[16], myd[16];
#pragma unroll
  for (int j = 0; j < 16; j++) {
    int i = base + t + j * 256;
    if (t + j * 256 < cnt) {
      mys[j] = src[i];
      myd[j] = dst[i];
      atomicAdd(&hist[myd[j] >> 8], 1);
    } else {
      myd[j] = -1;
    }
  }
  __syncthreads();
  int myc = hist[t];  // this thread's bucket count (bucket id == t)
  // inclusive scan of hist in place
  for (int off = 1; off < 256; off <<= 1) {
    int tmp = (t >= off) ? hist[t - off] : 0;
    __syncthreads();
    hist[t] += tmp;
    __syncthreads();
  }
  int excl = hist[t] - myc;
  startb[t] = excl;
  cur[t] = excl;
  __syncthreads();

  // scatter tile into LDS, sorted by bucket
#pragma unroll
  for (int j = 0; j < 16; j++) {
    if (myd[j] >= 0) {
      int b = myd[j] >> 8;
      int p = atomicAdd(&cur[b], 1);
      ent[p] = ((u32)myd[j] << 16) | (u32)mys[j];
      ebk[p] = (u8)b;
    }
  }
  __syncthreads();

  // reserve global space per bucket (order within bucket is irrelevant)
  if (t < nbuck && myc > 0) gbase[t] = atomicAdd(&cursors[t], myc);
  __syncthreads();

  // copy out: contiguous within each bucket-run
#pragma unroll
  for (int j = 0; j < 16; j++) {
    int p = t + j * 256;
    if (p < cnt) {
      int b = ebk[p];
      int gpos = gbase[b] + (p - startb[b]);
      if (gpos < (b + 1) * BCAP) binned[gpos] = ent[p];
    }
  }
}

// Exclusive scan of per-bucket counts -> global edge base per bucket.
__global__ __launch_bounds__(256) void scan_buckets_kernel(
    const int* __restrict__ cursors, int* __restrict__ edgeBase, int nbuck) {
  __shared__ int s[256];
  int t = threadIdx.x;
  int c = 0;
  if (t < nbuck) {
    c = cursors[t] - t * BCAP;
    if (c < 0) c = 0;
    if (c > BCAP) c = BCAP;
  }
  s[t] = c;
  __syncthreads();
  for (int off = 1; off < 256; off <<= 1) {
    int tmp = (t >= off) ? s[t - off] : 0;
    __syncthreads();
    s[t] += tmp;
    __syncthreads();
  }
  edgeBase[t] = s[t] - c;
}

// Pass 2: one block per bucket builds the CSR segment entirely in LDS,
// then writes csr_src (coalesced) and offsets (coalesced).
__global__ __launch_bounds__(256) void csr_kernel(
    const u32* __restrict__ binned, const int* __restrict__ cursors,
    const int* __restrict__ edgeBase, u16* __restrict__ csr_src,
    int* __restrict__ offsets, int n_nodes, int nbuck) {
  __shared__ int deg[256];
  __shared__ int cur[256];
  __shared__ u16 lcsr[BCAP];
  int b = blockIdx.x, t = threadIdx.x;
  int cnt = cursors[b] - b * BCAP;
  if (cnt < 0) cnt = 0;
  if (cnt > BCAP) cnt = BCAP;
  int ebase = edgeBase[b];
  int nodeBase = b << 8;
  int nn = n_nodes - nodeBase;
  if (nn > 256) nn = 256;

  deg[t] = 0;
  __syncthreads();
  const u32* be = binned + (size_t)b * BCAP;
  for (int i = t; i < cnt; i += 256)
    atomicAdd(&deg[(be[i] >> 16) - nodeBase], 1);
  __syncthreads();
  int myd = deg[t];
  for (int off = 1; off < 256; off <<= 1) {
    int tmp = (t >= off) ? deg[t - off] : 0;
    __syncthreads();
    deg[t] += tmp;
    __syncthreads();
  }
  int loff = deg[t] - myd;  // exclusive
  cur[t] = loff;
  if (t < nn) offsets[nodeBase + t] = ebase + loff;
  if (b == nbuck - 1 && t == 0) offsets[n_nodes] = ebase + cnt;
  __syncthreads();

  for (int i = t; i < cnt; i += 256) {
    u32 e = be[i];
    int ln = (e >> 16) - nodeBase;
    int p = atomicAdd(&cur[ln], 1);
    lcsr[p] = (u16)(e & 0xffffu);
  }
  __syncthreads();
  for (int i = t; i < cnt; i += 256) csr_src[ebase + i] = lcsr[i];
}

// ===========================================================================
// Gather v4 (bf16 rows): wave = node; 8 subgroups of 8 lanes take CONTIGUOUS
// edge runs, unrolled x4 with 4 accumulator sets -> 4 independent 128B row
// loads in flight per subgroup iteration. fp32 accumulate -> agg fp32.
// ===========================================================================
#define ACC8(a, r)                                                       \
  a[0] += __uint_as_float(r.x << 16); a[1] += __uint_as_float(r.x & 0xffff0000u); \
  a[2] += __uint_as_float(r.y << 16); a[3] += __uint_as_float(r.y & 0xffff0000u); \
  a[4] += __uint_as_float(r.z << 16); a[5] += __uint_as_float(r.z & 0xffff0000u); \
  a[6] += __uint_as_float(r.w << 16); a[7] += __uint_as_float(r.w & 0xffff0000u);

__global__ __launch_bounds__(256) void gather_kernel(
    const u16* __restrict__ h, const int* __restrict__ offsets,
    const u16* __restrict__ csr_src, float* __restrict__ agg, int n_nodes) {
  int node = blockIdx.x * 4 + (threadIdx.x >> 6);
  int lane = threadIdx.x & 63;
  int sub = lane >> 3;
  int fo = (lane & 7) * 8;
  if (node >= n_nodes) return;
  int start = offsets[node];
  int end = offsets[node + 1];
  int len = end - start;
  int chunk = (len + 7) >> 3;
  int i = start + sub * chunk;
  int re = i + chunk;
  if (re > end) re = end;

  float a0[8] = {0,0,0,0,0,0,0,0}, a1[8] = {0,0,0,0,0,0,0,0};
  float a2[8] = {0,0,0,0,0,0,0,0}, a3[8] = {0,0,0,0,0,0,0,0};
  for (; i + 3 < re; i += 4) {
    int s0 = csr_src[i], s1 = csr_src[i + 1], s2 = csr_src[i + 2], s3 = csr_src[i + 3];
    uint4 r0 = *(const uint4*)(h + ((size_t)s0 << 6) + fo);
    uint4 r1 = *(const uint4*)(h + ((size_t)s1 << 6) + fo);
    uint4 r2 = *(const uint4*)(h + ((size_t)s2 << 6) + fo);
    uint4 r3 = *(const uint4*)(h + ((size_t)s3 << 6) + fo);
    ACC8(a0, r0) ACC8(a1, r1) ACC8(a2, r2) ACC8(a3, r3)
  }
  for (; i < re; i++) {
    int s0 = csr_src[i];
    uint4 r0 = *(const uint4*)(h + ((size_t)s0 << 6) + fo);
    ACC8(a0, r0)
  }
#pragma unroll
  for (int k = 0; k < 8; k++) a0[k] += a1[k] + a2[k] + a3[k];
#pragma unroll
  for (int k = 0; k < 8; k++) {
    a0[k] += __shfl_xor(a0[k], 8);
    a0[k] += __shfl_xor(a0[k], 16);
    a0[k] += __shfl_xor(a0[k], 32);
  }
  if (sub == 0) {
    float* ap = agg + ((size_t)node << 6) + fo;
    *(float4*)(ap)     = make_float4(a0[0], a0[1], a0[2], a0[3]);
    *(float4*)(ap + 4) = make_float4(a0[4], a0[5], a0[6], a0[7]);
  }
}

// ===========================================================================
// Dense: out = [relu](agg @ W_rel + b + h @ W_root). Weights in registers
// (lane o holds column o), readlane broadcast, zero LDS. agg fp32, h/out bf16.
// ===========================================================================
__global__ __launch_bounds__(64) void dense_kernel(
    const float* __restrict__ agg, const u16* __restrict__ h,
    const float* __restrict__ Wrel, const float* __restrict__ brel,
    const float* __restrict__ Wroot, u16* __restrict__ out,
    int n_nodes, int do_relu) {
  int lane = threadIdx.x;
  float wrel[D], wroot[D];
#pragma unroll
  for (int k = 0; k < D; k++) {
    wrel[k] = Wrel[k * D + lane];
    wroot[k] = Wroot[k * D + lane];
  }
  float b = brel[lane];

  for (int n = blockIdx.x; n < n_nodes; n += gridDim.x) {
    float va = agg[((size_t)n << 6) + lane];
    float vx = bf2f(h[((size_t)n << 6) + lane]);
    float acc = b;
#pragma unroll
    for (int k = 0; k < D; k++) {
      float sa = __int_as_float(__builtin_amdgcn_readlane(__float_as_int(va), k));
      float sx = __int_as_float(__builtin_amdgcn_readlane(__float_as_int(vx), k));
      acc = fmaf(sa, wrel[k], acc);
      acc = fmaf(sx, wroot[k], acc);
    }
    if (do_relu) acc = fmaxf(acc, 0.0f);
    out[((size_t)n << 6) + lane] = f2bf(acc);
  }
}

// ===========================================================================
// Pool: batch sorted -> contiguous segments; one block per graph.
// ===========================================================================
__global__ __launch_bounds__(256) void pool_mean_kernel(
    const u16* __restrict__ h, const int* __restrict__ batch,
    float* __restrict__ pooled, int n_nodes) {
  __shared__ int seg[2];
  __shared__ float red[256];
  int g = blockIdx.x;
  if (threadIdx.x < 2) {
    int target = g + (int)threadIdx.x;
    int lo = 0, hi = n_nodes;
    while (lo < hi) {
      int mid = (lo + hi) >> 1;
      if (batch[mid] < target) lo = mid + 1; else hi = mid;
    }
    seg[threadIdx.x] = lo;
  }
  __syncthreads();
  int start = seg[0], end = seg[1];
  int f = threadIdx.x & 63, sub = threadIdx.x >> 6;
  float acc = 0.0f;
  for (int n = start + sub; n < end; n += 4) acc += bf2f(h[((size_t)n << 6) + f]);
  red[threadIdx.x] = acc;
  __syncthreads();
  if (sub == 0) {
    float v = red[f] + red[64 + f] + red[128 + f] + red[192 + f];
    float cnt = (float)(end - start);
    pooled[g * D + f] = v / fmaxf(cnt, 1.0f);
  }
}

__global__ __launch_bounds__(256) void final_kernel(
    const float* __restrict__ pooled, const float* __restrict__ Wlin,
    const float* __restrict__ blin, float* __restrict__ out) {
  int idx = blockIdx.x * 256 + threadIdx.x;
  if (idx >= N_GRAPHS * D_OUT) return;
  int g = idx >> 4;
  int o = idx & 15;
  float acc = blin[o];
#pragma unroll
  for (int k = 0; k < D; k++) {
    acc = fmaf(pooled[g * D + k], Wlin[k * D_OUT + o], acc);
  }
  out[idx] = acc;
}

extern "C" void kernel_launch(void* const* d_in, const int* in_sizes, int n_in,
                              void* d_out, int out_size, void* d_ws, size_t ws_size,
                              hipStream_t stream) {
  const float* x     = (const float*)d_in[0];
  const int*   ei    = (const int*)d_in[1];
  const int*   batch = (const int*)d_in[3];
  const float* Wrel1 = (const float*)d_in[4];
  const float* brel1 = (const float*)d_in[5];
  const float* Wroot1= (const float*)d_in[6];
  const float* Wrel2 = (const float*)d_in[7];
  const float* brel2 = (const float*)d_in[8];
  const float* Wroot2= (const float*)d_in[9];
  const float* Wrel3 = (const float*)d_in[10];
  const float* brel3 = (const float*)d_in[11];
  const float* Wroot3= (const float*)d_in[12];
  const float* Wlin  = (const float*)d_in[13];
  const float* blin  = (const float*)d_in[14];
  float* out = (float*)d_out;

  const int n_edges = in_sizes[1] / 2;
  const int n_nodes = in_sizes[0] / D;
  const int* src = ei;
  const int* dst = ei + n_edges;
  const int nbuck = (n_nodes + 255) >> 8;  // 196

  // ---- workspace carve-up (binned and agg alias: binned dead after csr) ----
  char* p = (char*)d_ws;
  size_t binned_bytes = (size_t)nbuck * BCAP * sizeof(u32);        // ~12.85MB
  size_t agg_bytes = (size_t)n_nodes * D * sizeof(float);          // 12.8MB
  u32* binned  = (u32*)p;
  float* agg   = (float*)p;
  p += (binned_bytes > agg_bytes ? binned_bytes : agg_bytes);
  float* pooled = (float*)p; p += (size_t)N_GRAPHS * D * sizeof(float);
  int* cursors  = (int*)p;   p += 256 * sizeof(int);
  int* edgeBase = (int*)p;   p += 256 * sizeof(int);
  int* offsets  = (int*)p;   p += (size_t)(n_nodes + 4) * sizeof(int);
  u16* hX       = (u16*)p;   p += (size_t)n_nodes * D * sizeof(u16);
  u16* h1       = (u16*)p;   p += (size_t)n_nodes * D * sizeof(u16);
  u16* h2       = (u16*)p;   p += (size_t)n_nodes * D * sizeof(u16);
  u16* h3       = (u16*)p;   p += (size_t)n_nodes * D * sizeof(u16);
  u16* csr_src  = (u16*)p;   p += (size_t)n_edges * sizeof(u16);

  const int bin_blocks = (n_edges + TILE - 1) / TILE;
  const int gath_blocks = (n_nodes + 3) / 4;
  const int dense_blocks = 3072;
  const int cvt_n4 = n_nodes * D / 4;

  // ---- CSR build (LDS counting sort) + x->bf16 ----
  init_cursors_kernel<<<1, 256, 0, stream>>>(cursors, nbuck);
  cvt_bf16_kernel<<<(cvt_n4 + 255) / 256, 256, 0, stream>>>(x, hX, cvt_n4);
  bin_kernel<<<bin_blocks, 256, 0, stream>>>(src, dst, cursors, binned, n_edges, nbuck);
  scan_buckets_kernel<<<1, 256, 0, stream>>>(cursors, edgeBase, nbuck);
  csr_kernel<<<nbuck, 256, 0, stream>>>(binned, cursors, edgeBase, csr_src, offsets, n_nodes, nbuck);

  // ---- layer 1 ----
  gather_kernel<<<gath_blocks, 256, 0, stream>>>(hX, offsets, csr_src, agg, n_nodes);
  dense_kernel<<<dense_blocks, 64, 0, stream>>>(agg, hX, Wrel1, brel1, Wroot1, h1, n_nodes, 1);

  // ---- layer 2 ----
  gather_kernel<<<gath_blocks, 256, 0, stream>>>(h1, offsets, csr_src, agg, n_nodes);
  dense_kernel<<<dense_blocks, 64, 0, stream>>>(agg, h1, Wrel2, brel2, Wroot2, h2, n_nodes, 1);

  // ---- layer 3 (no relu) ----
  gather_kernel<<<gath_blocks, 256, 0, stream>>>(h2, offsets, csr_src, agg, n_nodes);
  dense_kernel<<<dense_blocks, 64, 0, stream>>>(agg, h2, Wrel3, brel3, Wroot3, h3, n_nodes, 0);

  // ---- pool + final linear ----
  pool_mean_kernel<<<N_GRAPHS, 256, 0, stream>>>(h3, batch, pooled, n_nodes);
  final_kernel<<<(N_GRAPHS * D_OUT + 255) / 256, 256, 0, stream>>>(pooled, Wlin, blin, out);
}